// Round 4
// baseline (253.863 us; speedup 1.0000x reference)
//
#include <hip/hip_runtime.h>
#include <math.h>

#define IGN 255
constexpr int NC = 19;
constexpr int HWsz = 512 * 1024;
constexpr int NPIX = 8 * HWsz;

typedef float v2f __attribute__((ext_vector_type(2)));
typedef int v2i __attribute__((ext_vector_type(2)));
typedef float v4f __attribute__((ext_vector_type(4)));
typedef unsigned v4u __attribute__((ext_vector_type(4)));

struct Ctl {
  double total;
  unsigned n_valid, cnt, done, pad;
};

constexpr size_t H0 = 256;               // 2048 u32
constexpr size_t H1 = H0 + 2048 * 4;     // 2048 u32
constexpr size_t H2 = H1 + 2048 * 4;     // 1024 u32
constexpr size_t LOSS_OFF = 65536;       // NPIX floats

__device__ inline unsigned flip_key(unsigned u) {
  unsigned mask = (unsigned)((int)u >> 31) | 0x80000000u;
  return u ^ mask;
}
__device__ inline float unflip_val(unsigned k) {
  unsigned u = (k & 0x80000000u) ? (k ^ 0x80000000u) : ~k;
  return __uint_as_float(u);
}
__device__ inline unsigned compute_k(unsigned nv) {
  int nk = (int)(0.3f * (float)nv);
  int mk = (100000 < (int)nv) ? 100000 : (int)nv;
  if (nk < mk) nk = mk;
  if (nk > (int)nv) nk = (int)nv;
  return (unsigned)nk;
}

// Per-block redundant selection scan over a global histogram.
template <int NB>
__device__ inline void selscan(const unsigned* __restrict__ hist, unsigned k,
                               unsigned& bin, unsigned& kk) {
  constexpr int BPT = NB / 256;
  __shared__ unsigned ts[256];
  __shared__ unsigned bb[2];
  int t = threadIdx.x;
  unsigned local[BPT];
  unsigned lsum = 0;
#pragma unroll
  for (int j = 0; j < BPT; ++j) { local[j] = hist[t * BPT + j]; lsum += local[j]; }
  ts[t] = lsum;
  __syncthreads();
  for (int off = 1; off < 256; off <<= 1) {
    unsigned add = (t + off < 256) ? ts[t + off] : 0u;
    __syncthreads();
    ts[t] += add;
    __syncthreads();
  }
  unsigned above = ts[t] - lsum;
  if (t == 0) { bb[0] = 0xFFFFFFFFu; bb[1] = 0u; }
  __syncthreads();
  if (k > 0) {
#pragma unroll
    for (int j = BPT - 1; j >= 0; --j) {
      unsigned cb = local[j];
      unsigned tot = above + cb;
      if (above < k && tot >= k) { bb[0] = (unsigned)(t * BPT + j); bb[1] = k - above; }
      above = tot;
    }
  }
  __syncthreads();
  bin = bb[0];
  kk = bb[1];
  __syncthreads();
}

__global__ void k_init(unsigned char* ws) {
  Ctl* ctl = (Ctl*)ws;
  unsigned* h = (unsigned*)(ws + H0);
  int t = threadIdx.x;
  if (t == 0) { ctl->total = 0.0; ctl->n_valid = 0; ctl->cnt = 0; ctl->done = 0; }
  for (int i = t; i < 5120; i += 256) h[i] = 0;
}

// 2 pixels per thread: 19 x v2f = 38 data VGPRs -> high occupancy.
__global__ __launch_bounds__(256, 6) void k_loss(const float* __restrict__ logits,
                                                 const int* __restrict__ labels,
                                                 unsigned char* __restrict__ ws) {
  Ctl* ctl = (Ctl*)ws;
  float* loss = (float*)(ws + LOSS_OFF);
  unsigned* h0 = (unsigned*)(ws + H0);
  __shared__ unsigned lh[2048];
  __shared__ unsigned red[256];
  for (int i = threadIdx.x; i < 2048; i += 256) lh[i] = 0;
  __syncthreads();

  int tid = blockIdx.x * 256 + threadIdx.x;
  int n0 = tid * 2;
  int b = n0 >> 19;                       // / HWsz
  int hw = n0 & (HWsz - 1);
  const float* base = logits + (size_t)(b * NC) * HWsz + hw;

  v2f v[NC];
#pragma unroll
  for (int c = 0; c < NC; ++c)
    v[c] = __builtin_nontemporal_load(reinterpret_cast<const v2f*>(base + (size_t)c * HWsz));

  v2f m = v[0];
#pragma unroll
  for (int c = 1; c < NC; ++c) {
    m[0] = fmaxf(m[0], v[c][0]); m[1] = fmaxf(m[1], v[c][1]);
  }
  v2f s = (v2f)(0.f);
#pragma unroll
  for (int c = 0; c < NC; ++c) {
    s[0] += __expf(v[c][0] - m[0]); s[1] += __expf(v[c][1] - m[1]);
  }
  v2f lse;
  lse[0] = m[0] + __logf(s[0]); lse[1] = m[1] + __logf(s[1]);

  v2i lab = *reinterpret_cast<const v2i*>(labels + n0);
  v2f vl = (v2f)(0.f);
#pragma unroll
  for (int c = 0; c < NC; ++c) {
    vl[0] = (lab[0] == c) ? v[c][0] : vl[0];
    vl[1] = (lab[1] == c) ? v[c][1] : vl[1];
  }
  v2f out;
  unsigned cnt = 0;
  out[0] = (lab[0] == IGN) ? -INFINITY : (lse[0] - vl[0]); cnt += (lab[0] != IGN);
  out[1] = (lab[1] == IGN) ? -INFINITY : (lse[1] - vl[1]); cnt += (lab[1] != IGN);
  *reinterpret_cast<v2f*>(loss + n0) = out;

  // fused hist pass 0 (top 11 bits of flipped key)
  atomicAdd(&lh[flip_key(__float_as_uint(out[0])) >> 21], 1u);
  atomicAdd(&lh[flip_key(__float_as_uint(out[1])) >> 21], 1u);

  red[threadIdx.x] = cnt;
  __syncthreads();
  for (int s2 = 128; s2 > 0; s2 >>= 1) {
    if (threadIdx.x < s2) red[threadIdx.x] += red[threadIdx.x + s2];
    __syncthreads();
  }
  if (threadIdx.x == 0 && red[0]) atomicAdd(&ctl->n_valid, red[0]);
  for (int i = threadIdx.x; i < 2048; i += 256)
    if (lh[i]) atomicAdd(&h0[i], lh[i]);
}

__global__ __launch_bounds__(256) void k_hist1(unsigned char* __restrict__ ws) {
  Ctl* ctl = (Ctl*)ws;
  const unsigned* keys = (const unsigned*)(ws + LOSS_OFF);
  unsigned* h0 = (unsigned*)(ws + H0);
  unsigned* h1 = (unsigned*)(ws + H1);
  __shared__ unsigned lh[2048];
  unsigned k0 = compute_k(ctl->n_valid);
  unsigned p0, k1;
  selscan<2048>(h0, k0, p0, k1);
  for (int i = threadIdx.x; i < 2048; i += 256) lh[i] = 0;
  __syncthreads();

  unsigned idx0 = blockIdx.x * 512 + threadIdx.x;
#pragma unroll
  for (int i = 0; i < 2; ++i) {
    v4u u = reinterpret_cast<const v4u*>(keys)[idx0 + i * 256];
#pragma unroll
    for (int j = 0; j < 4; ++j) {
      unsigned key = flip_key(u[j]);
      if ((key >> 21) == p0) atomicAdd(&lh[(key >> 10) & 0x7FFu], 1u);
    }
  }
  __syncthreads();
  for (int i = threadIdx.x; i < 2048; i += 256)
    if (lh[i]) atomicAdd(&h1[i], lh[i]);
}

__global__ __launch_bounds__(256) void k_hist2(unsigned char* __restrict__ ws) {
  Ctl* ctl = (Ctl*)ws;
  const unsigned* keys = (const unsigned*)(ws + LOSS_OFF);
  unsigned* h0 = (unsigned*)(ws + H0);
  unsigned* h1 = (unsigned*)(ws + H1);
  unsigned* h2 = (unsigned*)(ws + H2);
  __shared__ unsigned lh[1024];
  unsigned k0 = compute_k(ctl->n_valid);
  unsigned p0, k1, p1, k2;
  selscan<2048>(h0, k0, p0, k1);
  selscan<2048>(h1, k1, p1, k2);
  unsigned pp = (p0 << 11) | p1;
  for (int i = threadIdx.x; i < 1024; i += 256) lh[i] = 0;
  __syncthreads();

  unsigned idx0 = blockIdx.x * 512 + threadIdx.x;
#pragma unroll
  for (int i = 0; i < 2; ++i) {
    v4u u = reinterpret_cast<const v4u*>(keys)[idx0 + i * 256];
#pragma unroll
    for (int j = 0; j < 4; ++j) {
      unsigned key = flip_key(u[j]);
      if ((key >> 10) == pp) atomicAdd(&lh[key & 0x3FFu], 1u);
    }
  }
  __syncthreads();
  for (int i = threadIdx.x; i < 1024; i += 256)
    if (lh[i]) atomicAdd(&h2[i], lh[i]);
}

__global__ __launch_bounds__(256) void k_final(unsigned char* __restrict__ ws,
                                               float* __restrict__ out) {
  Ctl* ctl = (Ctl*)ws;
  const float* loss = (const float*)(ws + LOSS_OFF);
  unsigned* h0 = (unsigned*)(ws + H0);
  unsigned* h1 = (unsigned*)(ws + H1);
  unsigned* h2 = (unsigned*)(ws + H2);
  unsigned k0 = compute_k(ctl->n_valid);
  unsigned p0, k1, p1, k2, b2, kf;
  selscan<2048>(h0, k0, p0, k1);
  selscan<2048>(h1, k1, p1, k2);
  selscan<1024>(h2, k2, b2, kf);
  float thr = INFINITY;
  if (k0 > 0) thr = unflip_val((((p0 << 11) | p1) << 10) | b2);

  unsigned idx0 = blockIdx.x * 512 + threadIdx.x;
  float s = 0.f;
  unsigned c = 0;
#pragma unroll
  for (int i = 0; i < 2; ++i) {
    v4f v = reinterpret_cast<const v4f*>(loss)[idx0 + i * 256];
    if (v[0] >= thr) { s += v[0]; c++; }
    if (v[1] >= thr) { s += v[1]; c++; }
    if (v[2] >= thr) { s += v[2]; c++; }
    if (v[3] >= thr) { s += v[3]; c++; }
  }
  double sd = (double)s;
  for (int off = 32; off > 0; off >>= 1) {
    sd += __shfl_down(sd, off);
    c += __shfl_down(c, off);
  }
  __shared__ double sred[4];
  __shared__ unsigned cred[4];
  int wave = threadIdx.x >> 6, lane = threadIdx.x & 63;
  if (lane == 0) { sred[wave] = sd; cred[wave] = c; }
  __syncthreads();
  if (threadIdx.x == 0) {
    double st = sred[0] + sred[1] + sred[2] + sred[3];
    unsigned ct = cred[0] + cred[1] + cred[2] + cred[3];
    atomicAdd(&ctl->total, st);
    atomicAdd(&ctl->cnt, ct);
    __threadfence();
    unsigned prev = atomicAdd(&ctl->done, 1u);
    if (prev == gridDim.x - 1) {
      double tt = atomicAdd(&ctl->total, 0.0);
      unsigned cc = atomicAdd(&ctl->cnt, 0u);
      float r = 0.f;
      if (ctl->n_valid != 0) {
        if (cc < 1u) cc = 1u;
        r = (float)(tt / (double)cc);
      }
      out[0] = r;
    }
  }
}

extern "C" void kernel_launch(void* const* d_in, const int* in_sizes, int n_in,
                              void* d_out, int out_size, void* d_ws, size_t ws_size,
                              hipStream_t stream) {
  const float* logits = (const float*)d_in[0];
  const int* labels = (const int*)d_in[1];
  float* out = (float*)d_out;
  unsigned char* ws = (unsigned char*)d_ws;

  hipLaunchKernelGGL(k_init, dim3(1), dim3(256), 0, stream, ws);
  hipLaunchKernelGGL(k_loss, dim3(NPIX / 2 / 256), dim3(256), 0, stream, logits, labels, ws);
  hipLaunchKernelGGL(k_hist1, dim3(NPIX / 8 / 256), dim3(256), 0, stream, ws);
  hipLaunchKernelGGL(k_hist2, dim3(NPIX / 8 / 256), dim3(256), 0, stream, ws);
  hipLaunchKernelGGL(k_final, dim3(NPIX / 8 / 256), dim3(256), 0, stream, ws, out);
}

// Round 5
// 206.017 us; speedup vs baseline: 1.2322x; 1.2322x over previous
//
#include <hip/hip_runtime.h>
#include <math.h>

#define IGN 255
constexpr int NC = 19;
constexpr int HWsz = 512 * 1024;
constexpr int NPIX = 8 * HWsz;

typedef float v4f __attribute__((ext_vector_type(4)));
typedef int v4i __attribute__((ext_vector_type(4)));
typedef unsigned v4u __attribute__((ext_vector_type(4)));

struct Ctl {
  double total;
  unsigned n_valid, cnt, done, pad;
};

constexpr size_t H0 = 256;               // 2048 u32
constexpr size_t H1 = H0 + 2048 * 4;     // 2048 u32
constexpr size_t H2 = H1 + 2048 * 4;     // 1024 u32
constexpr size_t LOSS_OFF = 65536;       // NPIX floats

__device__ inline unsigned flip_key(unsigned u) {
  unsigned mask = (unsigned)((int)u >> 31) | 0x80000000u;
  return u ^ mask;
}
__device__ inline float unflip_val(unsigned k) {
  unsigned u = (k & 0x80000000u) ? (k ^ 0x80000000u) : ~k;
  return __uint_as_float(u);
}
__device__ inline unsigned compute_k(unsigned nv) {
  int nk = (int)(0.3f * (float)nv);
  int mk = (100000 < (int)nv) ? 100000 : (int)nv;
  if (nk < mk) nk = mk;
  if (nk > (int)nv) nk = (int)nv;
  return (unsigned)nk;
}

// Per-block redundant selection scan over a global histogram.
template <int NB>
__device__ inline void selscan(const unsigned* __restrict__ hist, unsigned k,
                               unsigned& bin, unsigned& kk) {
  constexpr int BPT = NB / 256;
  __shared__ unsigned ts[256];
  __shared__ unsigned bb[2];
  int t = threadIdx.x;
  unsigned local[BPT];
  unsigned lsum = 0;
#pragma unroll
  for (int j = 0; j < BPT; ++j) { local[j] = hist[t * BPT + j]; lsum += local[j]; }
  ts[t] = lsum;
  __syncthreads();
  for (int off = 1; off < 256; off <<= 1) {
    unsigned add = (t + off < 256) ? ts[t + off] : 0u;
    __syncthreads();
    ts[t] += add;
    __syncthreads();
  }
  unsigned above = ts[t] - lsum;
  if (t == 0) { bb[0] = 0xFFFFFFFFu; bb[1] = 0u; }
  __syncthreads();
  if (k > 0) {
#pragma unroll
    for (int j = BPT - 1; j >= 0; --j) {
      unsigned cb = local[j];
      unsigned tot = above + cb;
      if (above < k && tot >= k) { bb[0] = (unsigned)(t * BPT + j); bb[1] = k - above; }
      above = tot;
    }
  }
  __syncthreads();
  bin = bb[0];
  kk = bb[1];
  __syncthreads();
}

__global__ void k_init(unsigned char* ws) {
  Ctl* ctl = (Ctl*)ws;
  unsigned* h = (unsigned*)(ws + H0);
  int t = threadIdx.x;
  if (t == 0) { ctl->total = 0.0; ctl->n_valid = 0; ctl->cnt = 0; ctl->done = 0; }
  for (int i = t; i < 5120; i += 256) h[i] = 0;
}

// Class-sequential online softmax: 16 px/thread, one contiguous 4KB run per
// class per wave. Avoids the 19-way same-L1-set burst of the co-aligned
// (2MB-stride) class streams.
__global__ __launch_bounds__(256) void k_loss(const float* __restrict__ logits,
                                              const int* __restrict__ labels,
                                              unsigned char* __restrict__ ws) {
  Ctl* ctl = (Ctl*)ws;
  float* loss = (float*)(ws + LOSS_OFF);
  unsigned* h0 = (unsigned*)(ws + H0);
  __shared__ unsigned lh[2048];
  __shared__ unsigned red[256];
  for (int i = threadIdx.x; i < 2048; i += 256) lh[i] = 0;
  __syncthreads();

  int t = threadIdx.x;
  int base = blockIdx.x * 4096;           // 4096 px per block; divides HWsz
  int b = base >> 19;                     // image index (constant per block)
  int hw = base & (HWsz - 1);
  const float* lbase = logits + (size_t)(b * NC) * HWsz + hw + t * 4;

  v4i labv[4];
#pragma unroll
  for (int q = 0; q < 4; ++q)
    labv[q] = *reinterpret_cast<const v4i*>(labels + base + q * 1024 + t * 4);

  v4f m[4], s[4], vl[4];
  // class 0 initializes the online state
#pragma unroll
  for (int q = 0; q < 4; ++q) {
    v4f v = *reinterpret_cast<const v4f*>(lbase + q * 1024);
    m[q] = v;
    s[q] = (v4f)(1.f);
#pragma unroll
    for (int j = 0; j < 4; ++j)
      vl[q][j] = (labv[q][j] == 0) ? v[j] : 0.f;
  }

#pragma unroll 1
  for (int c = 1; c < NC; ++c) {
    const float* cb = lbase + (size_t)c * HWsz;
    v4f v[4];
#pragma unroll
    for (int q = 0; q < 4; ++q)
      v[q] = *reinterpret_cast<const v4f*>(cb + q * 1024);
#pragma unroll
    for (int q = 0; q < 4; ++q) {
#pragma unroll
      for (int j = 0; j < 4; ++j) {
        float x = v[q][j];
        float mo = m[q][j];
        float mn = fmaxf(mo, x);
        s[q][j] = s[q][j] * __expf(mo - mn) + __expf(x - mn);
        m[q][j] = mn;
        vl[q][j] = (labv[q][j] == c) ? x : vl[q][j];
      }
    }
  }

  unsigned cnt = 0;
#pragma unroll
  for (int q = 0; q < 4; ++q) {
    v4f o;
#pragma unroll
    for (int j = 0; j < 4; ++j) {
      int lb = labv[q][j];
      float lse = m[q][j] + __logf(s[q][j]);
      o[j] = (lb == IGN) ? -INFINITY : (lse - vl[q][j]);
      cnt += (lb != IGN);
      atomicAdd(&lh[flip_key(__float_as_uint(o[j])) >> 21], 1u);
    }
    *reinterpret_cast<v4f*>(loss + base + q * 1024 + t * 4) = o;
  }

  red[t] = cnt;
  __syncthreads();
  for (int s2 = 128; s2 > 0; s2 >>= 1) {
    if (t < s2) red[t] += red[t + s2];
    __syncthreads();
  }
  if (t == 0 && red[0]) atomicAdd(&ctl->n_valid, red[0]);
  for (int i = t; i < 2048; i += 256)
    if (lh[i]) atomicAdd(&h0[i], lh[i]);
}

__global__ __launch_bounds__(256) void k_hist1(unsigned char* __restrict__ ws) {
  Ctl* ctl = (Ctl*)ws;
  const unsigned* keys = (const unsigned*)(ws + LOSS_OFF);
  unsigned* h0 = (unsigned*)(ws + H0);
  unsigned* h1 = (unsigned*)(ws + H1);
  __shared__ unsigned lh[2048];
  unsigned k0 = compute_k(ctl->n_valid);
  unsigned p0, k1;
  selscan<2048>(h0, k0, p0, k1);
  for (int i = threadIdx.x; i < 2048; i += 256) lh[i] = 0;
  __syncthreads();

  unsigned idx0 = blockIdx.x * 512 + threadIdx.x;
#pragma unroll
  for (int i = 0; i < 2; ++i) {
    v4u u = reinterpret_cast<const v4u*>(keys)[idx0 + i * 256];
#pragma unroll
    for (int j = 0; j < 4; ++j) {
      unsigned key = flip_key(u[j]);
      if ((key >> 21) == p0) atomicAdd(&lh[(key >> 10) & 0x7FFu], 1u);
    }
  }
  __syncthreads();
  for (int i = threadIdx.x; i < 2048; i += 256)
    if (lh[i]) atomicAdd(&h1[i], lh[i]);
}

__global__ __launch_bounds__(256) void k_hist2(unsigned char* __restrict__ ws) {
  Ctl* ctl = (Ctl*)ws;
  const unsigned* keys = (const unsigned*)(ws + LOSS_OFF);
  unsigned* h0 = (unsigned*)(ws + H0);
  unsigned* h1 = (unsigned*)(ws + H1);
  unsigned* h2 = (unsigned*)(ws + H2);
  __shared__ unsigned lh[1024];
  unsigned k0 = compute_k(ctl->n_valid);
  unsigned p0, k1, p1, k2;
  selscan<2048>(h0, k0, p0, k1);
  selscan<2048>(h1, k1, p1, k2);
  unsigned pp = (p0 << 11) | p1;
  for (int i = threadIdx.x; i < 1024; i += 256) lh[i] = 0;
  __syncthreads();

  unsigned idx0 = blockIdx.x * 512 + threadIdx.x;
#pragma unroll
  for (int i = 0; i < 2; ++i) {
    v4u u = reinterpret_cast<const v4u*>(keys)[idx0 + i * 256];
#pragma unroll
    for (int j = 0; j < 4; ++j) {
      unsigned key = flip_key(u[j]);
      if ((key >> 10) == pp) atomicAdd(&lh[key & 0x3FFu], 1u);
    }
  }
  __syncthreads();
  for (int i = threadIdx.x; i < 1024; i += 256)
    if (lh[i]) atomicAdd(&h2[i], lh[i]);
}

__global__ __launch_bounds__(256) void k_final(unsigned char* __restrict__ ws,
                                               float* __restrict__ out) {
  Ctl* ctl = (Ctl*)ws;
  const float* loss = (const float*)(ws + LOSS_OFF);
  unsigned* h0 = (unsigned*)(ws + H0);
  unsigned* h1 = (unsigned*)(ws + H1);
  unsigned* h2 = (unsigned*)(ws + H2);
  unsigned k0 = compute_k(ctl->n_valid);
  unsigned p0, k1, p1, k2, b2, kf;
  selscan<2048>(h0, k0, p0, k1);
  selscan<2048>(h1, k1, p1, k2);
  selscan<1024>(h2, k2, b2, kf);
  float thr = INFINITY;
  if (k0 > 0) thr = unflip_val((((p0 << 11) | p1) << 10) | b2);

  unsigned idx0 = blockIdx.x * 512 + threadIdx.x;
  float s = 0.f;
  unsigned c = 0;
#pragma unroll
  for (int i = 0; i < 2; ++i) {
    v4f v = reinterpret_cast<const v4f*>(loss)[idx0 + i * 256];
    if (v[0] >= thr) { s += v[0]; c++; }
    if (v[1] >= thr) { s += v[1]; c++; }
    if (v[2] >= thr) { s += v[2]; c++; }
    if (v[3] >= thr) { s += v[3]; c++; }
  }
  double sd = (double)s;
  for (int off = 32; off > 0; off >>= 1) {
    sd += __shfl_down(sd, off);
    c += __shfl_down(c, off);
  }
  __shared__ double sred[4];
  __shared__ unsigned cred[4];
  int wave = threadIdx.x >> 6, lane = threadIdx.x & 63;
  if (lane == 0) { sred[wave] = sd; cred[wave] = c; }
  __syncthreads();
  if (threadIdx.x == 0) {
    double st = sred[0] + sred[1] + sred[2] + sred[3];
    unsigned ct = cred[0] + cred[1] + cred[2] + cred[3];
    atomicAdd(&ctl->total, st);
    atomicAdd(&ctl->cnt, ct);
    __threadfence();
    unsigned prev = atomicAdd(&ctl->done, 1u);
    if (prev == gridDim.x - 1) {
      double tt = atomicAdd(&ctl->total, 0.0);
      unsigned cc = atomicAdd(&ctl->cnt, 0u);
      float r = 0.f;
      if (ctl->n_valid != 0) {
        if (cc < 1u) cc = 1u;
        r = (float)(tt / (double)cc);
      }
      out[0] = r;
    }
  }
}

extern "C" void kernel_launch(void* const* d_in, const int* in_sizes, int n_in,
                              void* d_out, int out_size, void* d_ws, size_t ws_size,
                              hipStream_t stream) {
  const float* logits = (const float*)d_in[0];
  const int* labels = (const int*)d_in[1];
  float* out = (float*)d_out;
  unsigned char* ws = (unsigned char*)d_ws;

  hipLaunchKernelGGL(k_init, dim3(1), dim3(256), 0, stream, ws);
  hipLaunchKernelGGL(k_loss, dim3(NPIX / 4096), dim3(256), 0, stream, logits, labels, ws);
  hipLaunchKernelGGL(k_hist1, dim3(NPIX / 8 / 256), dim3(256), 0, stream, ws);
  hipLaunchKernelGGL(k_hist2, dim3(NPIX / 8 / 256), dim3(256), 0, stream, ws);
  hipLaunchKernelGGL(k_final, dim3(NPIX / 8 / 256), dim3(256), 0, stream, ws, out);
}